// Round 9
// baseline (505.721 us; speedup 1.0000x reference)
//
#include <hip/hip_runtime.h>
#include <hip/hip_bf16.h>
#include <math.h>

// Problem: B=2, S=2048, D=1024, H=16, Hd=64. fp32 in/out.
constexpr int Bt   = 2;
constexpr int Sseq = 2048;
constexpr int Dm   = 1024;
constexpr int Hh   = 16;
constexpr int Mrows = Bt * Sseq;   // 4096
constexpr int Kd    = 1024;

// Q pre-scale: (1/sqrt(64)) * log2(e)  -> softmax done with exp2
constexpr float QSCALE = 0.18033688011112042f;

typedef __attribute__((ext_vector_type(8)))  short bf16x8;
typedef __attribute__((ext_vector_type(4)))  float f32x4;
typedef __attribute__((ext_vector_type(16))) float f32x16;

__device__ __forceinline__ ushort bfhi(float x) {
    __hip_bfloat16 h = __float2bfloat16(x);
    return *reinterpret_cast<ushort*>(&h);
}
__device__ __forceinline__ float bf2f(ushort u) {
    __hip_bfloat16 h;
    *reinterpret_cast<ushort*>(&h) = u;
    return __bfloat162float(h);
}
__device__ __forceinline__ void split2(float x, ushort& h, ushort& l) {
    h = bfhi(x);
    l = bfhi(x - bf2f(h));
}

// ============================================================================
// Prepass: fp32 -> (hi,lo) bf16 planes.
// ============================================================================
__global__ __launch_bounds__(256)
void split_fp32(const float* __restrict__ in, ushort* __restrict__ hi,
                ushort* __restrict__ lo, int n4)
{
    int i = blockIdx.x * blockDim.x + threadIdx.x;
    int stride = gridDim.x * blockDim.x;
    for (; i < n4; i += stride) {
        float4 v = ((const float4*)in)[i];
        float vv[4] = {v.x, v.y, v.z, v.w};
        ushort hs[4], ls[4];
        #pragma unroll
        for (int j = 0; j < 4; ++j) split2(vv[j], hs[j], ls[j]);
        *(ushort4*)&hi[i * 4] = make_ushort4(hs[0], hs[1], hs[2], hs[3]);
        *(ushort4*)&lo[i * 4] = make_ushort4(ls[0], ls[1], ls[2], ls[3]);
    }
}

// ============================================================================
// Shared GEMM epilogue: MODE 0 -> qk/vt split planes (Q pre-scaled by QSCALE,
// V transposed), MODE 1 -> fp32 C. C/D frag layout verified r3+.
// ============================================================================
template<int MODE>
__device__ __forceinline__ void gemm_epilogue(
    f32x4 (&acc)[4][4], int m0, int j0, int wr, int wc, int rl, int kq,
    const float* b0, const float* b1, const float* b2,
    float* Cf, ushort* qk_hi, ushort* qk_lo, ushort* vt_hi, ushort* vt_lo)
{
    const int wsel = j0 >> 10;
    const float* bias = (wsel == 0) ? b0 : ((wsel == 1) ? b1 : b2);
    #pragma unroll
    for (int i = 0; i < 4; ++i)
        #pragma unroll
        for (int j = 0; j < 4; ++j) {
            int col = j0 + wc * 64 + j * 16 + rl;
            float bv_ = bias[col & 1023];
            int token0 = m0 + wr * 64 + i * 16 + kq * 4;
            if constexpr (MODE == 1) {
                #pragma unroll
                for (int r = 0; r < 4; ++r)
                    Cf[(size_t)(token0 + r) * 1024 + col] = acc[i][j][r] + bv_;
            } else {
                if (col < 2048) {
                    float scale = (col < 1024) ? QSCALE : 1.0f;
                    #pragma unroll
                    for (int r = 0; r < 4; ++r) {
                        float val = (acc[i][j][r] + bv_) * scale;
                        ushort hs, ls;
                        split2(val, hs, ls);
                        size_t idx = (size_t)(token0 + r) * 2048 + col;
                        qk_hi[idx] = hs;
                        qk_lo[idx] = ls;
                    }
                } else {
                    int cc = col - 2048;
                    int hh = cc >> 6, dd = cc & 63;
                    int bb = token0 >> 11, s0 = token0 & 2047;
                    ushort hs[4], ls[4];
                    #pragma unroll
                    for (int r = 0; r < 4; ++r)
                        split2(acc[i][j][r] + bv_, hs[r], ls[r]);
                    size_t vrow = ((size_t)(bb * 16 + hh) * 64 + dd) * 2048 + s0;
                    *(ushort4*)(vt_hi + vrow) = make_ushort4(hs[0], hs[1], hs[2], hs[3]);
                    *(ushort4*)(vt_lo + vrow) = make_ushort4(ls[0], ls[1], ls[2], ls[3]);
                }
            }
        }
}

// ============================================================================
// Planes GEMM: A,W already split into hi/lo bf16 planes -> staging is pure
// load + swizzled ds_write (no split VALU). Tile/frag/swizzle = r8 verified.
// MODE 0: A=x planes, W=w1 planes (3072 rows). MODE 1: A=attn planes, W=w2.
// ============================================================================
template<int MODE>
__global__ __launch_bounds__(256)
void gemm_planes(const ushort* __restrict__ Ah, const ushort* __restrict__ Al,
                 const ushort* __restrict__ Wh, const ushort* __restrict__ Wl,
                 const float* __restrict__ b0, const float* __restrict__ b1,
                 const float* __restrict__ b2,
                 float* __restrict__ Cf,
                 ushort* __restrict__ qk_hi, ushort* __restrict__ qk_lo,
                 ushort* __restrict__ vt_hi, ushort* __restrict__ vt_lo)
{
    __shared__ alignas(16) ushort As[128 * 64];
    __shared__ alignas(16) ushort Bs[128 * 64];

    const int tid = threadIdx.x, lane = tid & 63, w = tid >> 6;

    const int gx = gridDim.x;
    int bid = blockIdx.y * gx + blockIdx.x;
    int cpx = (gx * gridDim.y) >> 3;
    int sb  = (bid & 7) * cpx + (bid >> 3);
    const int m0 = (sb / gx) * 128;
    const int j0 = (sb % gx) * 128;

    const int wr = w >> 1, wc = w & 1;
    const int rl = lane & 15, kq = lane >> 4;
    const int sw0 = rl & 7;

    const int srow  = tid >> 1;
    const int khalf = tid & 1;
    const int rsw   = srow & 7;

    const ushort* ga_h = Ah + (size_t)(m0 + srow) * Kd + khalf * 16;
    const ushort* ga_l = Al + (size_t)(m0 + srow) * Kd + khalf * 16;
    const ushort* gb_h = Wh + (size_t)(j0 + srow) * Kd + khalf * 16;
    const ushort* gb_l = Wl + (size_t)(j0 + srow) * Kd + khalf * 16;

    f32x4 acc[4][4] = {};
    bf16x8 sA[4], sB[4];   // [hi0,hi1,lo0,lo1] for A and B

    auto LOAD = [&](int k0) {
        sA[0] = *(const bf16x8*)(ga_h + k0);
        sA[1] = *(const bf16x8*)(ga_h + k0 + 8);
        sA[2] = *(const bf16x8*)(ga_l + k0);
        sA[3] = *(const bf16x8*)(ga_l + k0 + 8);
        sB[0] = *(const bf16x8*)(gb_h + k0);
        sB[1] = *(const bf16x8*)(gb_h + k0 + 8);
        sB[2] = *(const bf16x8*)(gb_l + k0);
        sB[3] = *(const bf16x8*)(gb_l + k0 + 8);
    };

    LOAD(0);
    for (int k0 = 0; k0 < Kd; k0 += 32) {
        __syncthreads();
        {
            ushort* pa = As + srow * 64;
            ushort* pb = Bs + srow * 64;
            #pragma unroll
            for (int t = 0; t < 2; ++t) {
                int s = khalf * 2 + t;
                *(bf16x8*)(pa + ((s    ) ^ rsw) * 8) = sA[t];
                *(bf16x8*)(pa + ((s + 4) ^ rsw) * 8) = sA[t + 2];
                *(bf16x8*)(pb + ((s    ) ^ rsw) * 8) = sB[t];
                *(bf16x8*)(pb + ((s + 4) ^ rsw) * 8) = sB[t + 2];
            }
        }
        __syncthreads();

        if (k0 + 32 < Kd) LOAD(k0 + 32);   // T14: in flight during MFMA

        bf16x8 ah[4], al[4], bh[4], bl[4];
        #pragma unroll
        for (int i = 0; i < 4; ++i) {
            const ushort* pa = As + (wr * 64 + i * 16 + rl) * 64;
            ah[i] = *(const bf16x8*)(pa + ((kq    ) ^ sw0) * 8);
            al[i] = *(const bf16x8*)(pa + ((kq + 4) ^ sw0) * 8);
            const ushort* pb = Bs + (wc * 64 + i * 16 + rl) * 64;
            bh[i] = *(const bf16x8*)(pb + ((kq    ) ^ sw0) * 8);
            bl[i] = *(const bf16x8*)(pb + ((kq + 4) ^ sw0) * 8);
        }
        __builtin_amdgcn_s_setprio(1);
        #pragma unroll
        for (int i = 0; i < 4; ++i)
            #pragma unroll
            for (int j = 0; j < 4; ++j) {
                acc[i][j] = __builtin_amdgcn_mfma_f32_16x16x32_bf16(ah[i], bh[j], acc[i][j], 0, 0, 0);
                acc[i][j] = __builtin_amdgcn_mfma_f32_16x16x32_bf16(ah[i], bl[j], acc[i][j], 0, 0, 0);
                acc[i][j] = __builtin_amdgcn_mfma_f32_16x16x32_bf16(al[i], bh[j], acc[i][j], 0, 0, 0);
            }
        __builtin_amdgcn_s_setprio(0);
    }

    gemm_epilogue<MODE>(acc, m0, j0, wr, wc, rl, kq, b0, b1, b2,
                        Cf, qk_hi, qk_lo, vt_hi, vt_lo);
}

// ============================================================================
// Fallback GEMM (r8-verified, in-kernel split), QSCALE epilogue.
// ============================================================================
template<int MODE>
__global__ __launch_bounds__(256)
void gemm_bf16x2(const float* __restrict__ A,
                 const float* __restrict__ W0, const float* __restrict__ W1,
                 const float* __restrict__ W2,
                 const float* __restrict__ b0, const float* __restrict__ b1,
                 const float* __restrict__ b2,
                 float* __restrict__ Cf,
                 ushort* __restrict__ qk_hi, ushort* __restrict__ qk_lo,
                 ushort* __restrict__ vt_hi, ushort* __restrict__ vt_lo)
{
    __shared__ alignas(16) ushort As[128 * 64];
    __shared__ alignas(16) ushort Bs[128 * 64];

    const int tid = threadIdx.x, lane = tid & 63, w = tid >> 6;

    const int gx = gridDim.x;
    int bid = blockIdx.y * gx + blockIdx.x;
    int cpx = (gx * gridDim.y) >> 3;
    int sb  = (bid & 7) * cpx + (bid >> 3);
    const int m0 = (sb / gx) * 128;
    const int j0 = (sb % gx) * 128;

    const int wsel = j0 >> 10;
    const float* __restrict__ W = (wsel == 0) ? W0 : ((wsel == 1) ? W1 : W2);
    const int jj0 = j0 & 1023;

    const int wr = w >> 1, wc = w & 1;
    const int rl = lane & 15, kq = lane >> 4;
    const int sw0 = rl & 7;

    const int srow  = tid >> 1;
    const int khalf = tid & 1;
    const int rsw   = srow & 7;

    const float* ga0 = A + (size_t)(m0  + srow) * Kd + khalf * 16;
    const float* gb0 = W + (size_t)(jj0 + srow) * Kd + khalf * 16;

    f32x4 acc[4][4] = {};
    float av[16], bv[16];

    #pragma unroll
    for (int p = 0; p < 4; ++p) {
        *(float4*)&av[p * 4] = *(const float4*)(ga0 + p * 4);
        *(float4*)&bv[p * 4] = *(const float4*)(gb0 + p * 4);
    }

    for (int k0 = 0; k0 < Kd; k0 += 32) {
        __syncthreads();
        {
            ushort* pa = As + srow * 64;
            ushort* pb = Bs + srow * 64;
            #pragma unroll
            for (int t = 0; t < 2; ++t) {
                bf16x8 hia, loa, hib, lob;
                #pragma unroll
                for (int e = 0; e < 8; ++e) {
                    float xa = av[t * 8 + e], xb = bv[t * 8 + e];
                    ushort ha, la, hb, lb;
                    split2(xa, ha, la); split2(xb, hb, lb);
                    hia[e] = (short)ha; loa[e] = (short)la;
                    hib[e] = (short)hb; lob[e] = (short)lb;
                }
                int s = khalf * 2 + t;
                *(bf16x8*)(pa + ((s    ) ^ rsw) * 8) = hia;
                *(bf16x8*)(pa + ((s + 4) ^ rsw) * 8) = loa;
                *(bf16x8*)(pb + ((s    ) ^ rsw) * 8) = hib;
                *(bf16x8*)(pb + ((s + 4) ^ rsw) * 8) = lob;
            }
        }
        __syncthreads();

        if (k0 + 32 < Kd) {
            #pragma unroll
            for (int p = 0; p < 4; ++p) {
                *(float4*)&av[p * 4] = *(const float4*)(ga0 + k0 + 32 + p * 4);
                *(float4*)&bv[p * 4] = *(const float4*)(gb0 + k0 + 32 + p * 4);
            }
        }

        bf16x8 ah[4], al[4], bh[4], bl[4];
        #pragma unroll
        for (int i = 0; i < 4; ++i) {
            const ushort* pa = As + (wr * 64 + i * 16 + rl) * 64;
            ah[i] = *(const bf16x8*)(pa + ((kq    ) ^ sw0) * 8);
            al[i] = *(const bf16x8*)(pa + ((kq + 4) ^ sw0) * 8);
            const ushort* pb = Bs + (wc * 64 + i * 16 + rl) * 64;
            bh[i] = *(const bf16x8*)(pb + ((kq    ) ^ sw0) * 8);
            bl[i] = *(const bf16x8*)(pb + ((kq + 4) ^ sw0) * 8);
        }
        __builtin_amdgcn_s_setprio(1);
        #pragma unroll
        for (int i = 0; i < 4; ++i)
            #pragma unroll
            for (int j = 0; j < 4; ++j) {
                acc[i][j] = __builtin_amdgcn_mfma_f32_16x16x32_bf16(ah[i], bh[j], acc[i][j], 0, 0, 0);
                acc[i][j] = __builtin_amdgcn_mfma_f32_16x16x32_bf16(ah[i], bl[j], acc[i][j], 0, 0, 0);
                acc[i][j] = __builtin_amdgcn_mfma_f32_16x16x32_bf16(al[i], bh[j], acc[i][j], 0, 0, 0);
            }
        __builtin_amdgcn_s_setprio(0);
    }

    gemm_epilogue<MODE>(acc, m0, j0, wr, wc, rl, kq, b0, b1, b2,
                        Cf, qk_hi, qk_lo, vt_hi, vt_lo);
}

// ============================================================================
// r9 attention: 64-q / 2-wave blocks (finer balance), 32x32 swapped-QK^T,
// exp2-domain softmax (Q pre-scaled by QSCALE), bf16x2 3-term (r8-verified
// inner math). WSPLIT: write O as hi/lo planes (feeds planes gemm1) or fp32.
// ============================================================================
template<bool WSPLIT>
__global__ __launch_bounds__(128)
void attn64(const ushort* __restrict__ qk_hi, const ushort* __restrict__ qk_lo,
            const ushort* __restrict__ vt_hi, const ushort* __restrict__ vt_lo,
            float* __restrict__ outF, ushort* __restrict__ oHi, ushort* __restrict__ oLo)
{
    __shared__ alignas(16) ushort Kh[4096], Kl[4096], Vh[4096], Vl[4096];

    const int xx = blockIdx.x;
    const int qt = (xx & 1) ? (xx >> 1) : (31 - (xx >> 1));   // balanced order
    const int h  = blockIdx.y, b = blockIdx.z;
    const int q0 = qt * 64;
    const int tid = threadIdx.x, l = tid & 63, w = tid >> 6;
    const int lo5 = l & 31, hi = l >> 5;

    // Q frags (B-operand), once
    bf16x8 qh[4], ql[4];
    {
        const size_t qrow = (size_t)(b * Sseq + q0 + w * 32 + lo5);
        #pragma unroll
        for (int s = 0; s < 4; ++s) {
            size_t g = qrow * 2048 + h * 64 + s * 16 + hi * 8;
            qh[s] = *(const bf16x8*)(qk_hi + g);
            ql[s] = *(const bf16x8*)(qk_lo + g);
        }
    }

    f32x16 accO[2] = {};
    float m_r = -INFINITY, l_r = 0.0f;
    const int qg = q0 + w * 32 + lo5;

    // staging: 128 threads; thread -> (row = tid>>1, half = tid&1: 4 slots)
    const int srow = tid >> 1, sh = tid & 1;
    const size_t kbase = (size_t)(b * Sseq) * 2048 + 1024 + h * 64 + sh * 32;
    const size_t vbase = ((size_t)((b * 16 + h) * 64) + srow) * 2048 + sh * 32;

    bf16x8 sKh[4], sKl[4], sVh[4], sVl[4];
    auto ISSUE = [&](int kv0) {
        size_t gk = kbase + (size_t)(kv0 + srow) * 2048;
        size_t gv = vbase + kv0;
        #pragma unroll
        for (int t = 0; t < 4; ++t) {
            sKh[t] = *(const bf16x8*)(qk_hi + gk + t * 8);
            sKl[t] = *(const bf16x8*)(qk_lo + gk + t * 8);
            sVh[t] = *(const bf16x8*)(vt_hi + gv + t * 8);
            sVl[t] = *(const bf16x8*)(vt_lo + gv + t * 8);
        }
    };

    const int NT = qt + 1;
    ISSUE(0);

    for (int kt = 0; kt < NT; ++kt) {
        __syncthreads();
        #pragma unroll
        for (int t = 0; t < 4; ++t) {
            int sw = (((sh * 4 + t) ^ (srow & 7))) * 8;
            *(bf16x8*)(Kh + srow * 64 + sw) = sKh[t];
            *(bf16x8*)(Kl + srow * 64 + sw) = sKl[t];
            *(bf16x8*)(Vh + srow * 64 + sw) = sVh[t];
            *(bf16x8*)(Vl + srow * 64 + sw) = sVl[t];
        }
        __syncthreads();

        if (kt + 1 < NT) ISSUE((kt + 1) * 64);   // T14

        const int kv0 = kt * 64;

        // QK^T swapped, 3-term
        f32x16 sc[2] = {};
        #pragma unroll
        for (int s = 0; s < 4; ++s) {
            __builtin_amdgcn_s_setprio(1);
            #pragma unroll
            for (int n = 0; n < 2; ++n) {
                int row = n * 32 + lo5;
                int sl = (s * 2 + hi) ^ (row & 7);
                bf16x8 kh = *(const bf16x8*)(Kh + row * 64 + sl * 8);
                bf16x8 kl = *(const bf16x8*)(Kl + row * 64 + sl * 8);
                sc[n] = __builtin_amdgcn_mfma_f32_32x32x16_bf16(kh, qh[s], sc[n], 0, 0, 0);
                sc[n] = __builtin_amdgcn_mfma_f32_32x32x16_bf16(kh, ql[s], sc[n], 0, 0, 0);
                sc[n] = __builtin_amdgcn_mfma_f32_32x32x16_bf16(kl, qh[s], sc[n], 0, 0, 0);
            }
            __builtin_amdgcn_s_setprio(0);
        }

        // causal mask (last tile only at 64-q granularity)
        if (kt == qt) {
            #pragma unroll
            for (int n = 0; n < 2; ++n)
                #pragma unroll
                for (int r = 0; r < 16; ++r) {
                    int kv = kv0 + n * 32 + ((r & 3) + 8 * (r >> 2) + 4 * hi);
                    if (kv > qg) sc[n][r] = -INFINITY;
                }
        }

        // online softmax (base-2 domain)
        float vmax = -INFINITY;
        #pragma unroll
        for (int n = 0; n < 2; ++n)
            #pragma unroll
            for (int r = 0; r < 16; ++r)
                vmax = fmaxf(vmax, sc[n][r]);
        vmax = fmaxf(vmax, __shfl_xor(vmax, 32));
        float mnew = fmaxf(m_r, vmax);
        float fs = exp2f(m_r - mnew);
        m_r = mnew;

        uint phk[2][8], plk[2][8];
        float sum = 0.0f;
        #pragma unroll
        for (int n = 0; n < 2; ++n)
            #pragma unroll
            for (int j = 0; j < 8; ++j) {
                float p0 = exp2f(sc[n][2 * j]     - mnew);
                float p1 = exp2f(sc[n][2 * j + 1] - mnew);
                sum += p0 + p1;
                ushort h0, l0, h1, l1;
                split2(p0, h0, l0);
                split2(p1, h1, l1);
                phk[n][j] = (uint)h0 | ((uint)h1 << 16);
                plk[n][j] = (uint)l0 | ((uint)l1 << 16);
            }
        sum += __shfl_xor(sum, 32);
        l_r = l_r * fs + sum;

        #pragma unroll
        for (int nd = 0; nd < 2; ++nd)
            #pragma unroll
            for (int r = 0; r < 16; ++r)
                accO[nd][r] *= fs;

        // PV: O^T += V^T . P
        #pragma unroll
        for (int step = 0; step < 4; ++step) {
            const int n  = step >> 1;
            const int io = (step & 1) * 4 + hi * 2;
            const int is = (step & 1) * 4 + (1 - hi) * 2;
            uint oh0 = phk[n][io], oh1 = phk[n][io + 1];
            uint ol0 = plk[n][io], ol1 = plk[n][io + 1];
            uint sh0 = (uint)__shfl_xor((int)phk[n][is],     32);
            uint sh1 = (uint)__shfl_xor((int)phk[n][is + 1], 32);
            uint sl0 = (uint)__shfl_xor((int)plk[n][is],     32);
            uint sl1 = (uint)__shfl_xor((int)plk[n][is + 1], 32);
            uint fh[4], fl[4];
            if (hi) { fh[0] = sh0; fh[1] = sh1; fh[2] = oh0; fh[3] = oh1;
                      fl[0] = sl0; fl[1] = sl1; fl[2] = ol0; fl[3] = ol1; }
            else    { fh[0] = oh0; fh[1] = oh1; fh[2] = sh0; fh[3] = sh1;
                      fl[0] = ol0; fl[1] = ol1; fl[2] = sl0; fl[3] = sl1; }
            bf16x8 ph = *reinterpret_cast<bf16x8*>(fh);
            bf16x8 pl = *reinterpret_cast<bf16x8*>(fl);

            __builtin_amdgcn_s_setprio(1);
            #pragma unroll
            for (int nd = 0; nd < 2; ++nd) {
                int row = nd * 32 + lo5;
                int sl_ = (step * 2 + hi) ^ (row & 7);
                bf16x8 vh = *(const bf16x8*)(Vh + row * 64 + sl_ * 8);
                bf16x8 vl = *(const bf16x8*)(Vl + row * 64 + sl_ * 8);
                accO[nd] = __builtin_amdgcn_mfma_f32_32x32x16_bf16(vh, ph, accO[nd], 0, 0, 0);
                accO[nd] = __builtin_amdgcn_mfma_f32_32x32x16_bf16(vh, pl, accO[nd], 0, 0, 0);
                accO[nd] = __builtin_amdgcn_mfma_f32_32x32x16_bf16(vl, ph, accO[nd], 0, 0, 0);
            }
            __builtin_amdgcn_s_setprio(0);
        }
    }

    // epilogue: O[q=lo5][d = 32*nd + 8*rg + 4*hi + (0..3)]
    {
        float inv = 1.0f / l_r;
        const size_t token = (size_t)(b * Sseq + q0 + w * 32 + lo5);
        #pragma unroll
        for (int nd = 0; nd < 2; ++nd)
            #pragma unroll
            for (int rg = 0; rg < 4; ++rg) {
                size_t idx = token * 1024 + h * 64 + nd * 32 + 8 * rg + 4 * hi;
                if constexpr (WSPLIT) {
                    ushort hs[4], ls[4];
                    #pragma unroll
                    for (int e = 0; e < 4; ++e)
                        split2(accO[nd][4 * rg + e] * inv, hs[e], ls[e]);
                    *(ushort4*)&oHi[idx] = make_ushort4(hs[0], hs[1], hs[2], hs[3]);
                    *(ushort4*)&oLo[idx] = make_ushort4(ls[0], ls[1], ls[2], ls[3]);
                } else {
                    float4 o = { accO[nd][4 * rg + 0] * inv, accO[nd][4 * rg + 1] * inv,
                                 accO[nd][4 * rg + 2] * inv, accO[nd][4 * rg + 3] * inv };
                    *(float4*)&outF[idx] = o;
                }
            }
    }
}

// ============================================================================
extern "C" void kernel_launch(void* const* d_in, const int* in_sizes, int n_in,
                              void* d_out, int out_size, void* d_ws, size_t ws_size,
                              hipStream_t stream)
{
    const float* x  = (const float*)d_in[0];
    const float* wq = (const float*)d_in[1];
    const float* bq = (const float*)d_in[2];
    const float* wk = (const float*)d_in[3];
    const float* bk = (const float*)d_in[4];
    const float* wv = (const float*)d_in[5];
    const float* bv = (const float*)d_in[6];
    const float* wo = (const float*)d_in[7];
    const float* bo = (const float*)d_in[8];
    float* out = (float*)d_out;

    const size_t NEED1 = 67108864;    // 64 MiB (fallback)
    const size_t NEED2 = 100663296;   // 96 MiB (planes path)
    if (ws_size < NEED1) return;

    char* p = (char*)d_ws;
    ushort* qk_hi = (ushort*)(p);
    ushort* qk_lo = (ushort*)(p + 16777216);
    ushort* vt_hi = (ushort*)(p + 33554432);
    ushort* vt_lo = (ushort*)(p + 41943040);

    if (ws_size >= NEED2) {
        ushort* at_hi = (ushort*)(p + 50331648);
        ushort* at_lo = (ushort*)(p + 58720256);
        ushort* xp_hi = (ushort*)(p + 67108864);
        ushort* xp_lo = (ushort*)(p + 75497472);
        ushort* w1_hi = (ushort*)(p + 83886080);
        ushort* w1_lo = (ushort*)(p + 90177536);
        ushort* w2_hi = (ushort*)(p + 96468992);
        ushort* w2_lo = (ushort*)(p + 98566144);

        split_fp32<<<1024, 256, 0, stream>>>(x,  xp_hi, xp_lo, 1048576);
        split_fp32<<<512,  256, 0, stream>>>(wq, w1_hi,           w1_lo,           262144);
        split_fp32<<<512,  256, 0, stream>>>(wk, w1_hi + 1048576, w1_lo + 1048576, 262144);
        split_fp32<<<512,  256, 0, stream>>>(wv, w1_hi + 2097152, w1_lo + 2097152, 262144);
        split_fp32<<<512,  256, 0, stream>>>(wo, w2_hi,           w2_lo,           262144);

        gemm_planes<0><<<dim3(24, 32), 256, 0, stream>>>(
            xp_hi, xp_lo, w1_hi, w1_lo, bq, bk, bv,
            nullptr, qk_hi, qk_lo, vt_hi, vt_lo);

        attn64<true><<<dim3(32, Hh, Bt), 128, 0, stream>>>(
            qk_hi, qk_lo, vt_hi, vt_lo, nullptr, at_hi, at_lo);

        gemm_planes<1><<<dim3(8, 32), 256, 0, stream>>>(
            at_hi, at_lo, w2_hi, w2_lo, bo, bo, bo,
            out, nullptr, nullptr, nullptr, nullptr);
    } else {
        float* attn = (float*)(p + 50331648);

        gemm_bf16x2<0><<<dim3(24, 32), 256, 0, stream>>>(
            x, wq, wk, wv, bq, bk, bv, nullptr, qk_hi, qk_lo, vt_hi, vt_lo);

        attn64<false><<<dim3(32, Hh, Bt), 128, 0, stream>>>(
            qk_hi, qk_lo, vt_hi, vt_lo, attn, nullptr, nullptr);

        gemm_bf16x2<1><<<dim3(8, 32), 256, 0, stream>>>(
            attn, wo, wo, wo, bo, bo, bo, out, nullptr, nullptr, nullptr, nullptr);
    }
}